// Round 2
// baseline (783.300 us; speedup 1.0000x reference)
//
#include <hip/hip_runtime.h>
#include <stdint.h>

// GAT encoder, MFMA version. B=8192 graphs, N=64 nodes, F=64.
// Matmuls (h@W, P@h') via mfma_f32_16x16x32_bf16; softmax/norm in fp32.
// One 256-thread block (4 waves) per graph. LDS ~50.8KB -> 3 blocks/CU.

typedef __attribute__((ext_vector_type(8))) short short8;
typedef __attribute__((ext_vector_type(4))) float floatx4;

#define NEGV -1e12f

static __device__ __forceinline__ uint32_t f2bf(float f) {
    uint32_t u = __builtin_bit_cast(uint32_t, f);
    return (u + 0x7FFFu + ((u >> 16) & 1u)) >> 16;   // RNE
}
static __device__ __forceinline__ float bf2f(uint32_t u) {
    return __builtin_bit_cast(float, u << 16);
}

// Pre-transpose + bf16-cast weights into d_ws:
//  block 0: w0t[h*16+o][f] = bf16(w0[h][f][o])   (concat-transposed, B-operand layout)
//  block 1: w1t[o][f]      = bf16(w1[f][o])
// Row stride 72 ushorts (144B) to match the LDS image exactly.
__global__ __launch_bounds__(256) void prep_weights(
    const float* __restrict__ w0g, const float* __restrict__ w1g,
    ushort* __restrict__ wt)
{
    const int b = blockIdx.x, tid = threadIdx.x;
    ushort* dst = wt + b * 4608;
    for (int i = tid; i < 4608; i += 256) {
        int ro = i / 72, c = i % 72;
        float v = 0.f;
        if (c < 64) v = (b == 0) ? w0g[(ro >> 4) * 1024 + c * 16 + (ro & 15)]
                                 : w1g[c * 64 + ro];
        dst[i] = (ushort)f2bf(v);
    }
}

__global__ __launch_bounds__(256) void gat_fused(
    const float* __restrict__ x, const int* __restrict__ fhi,
    const ushort* __restrict__ w0t, const ushort* __restrict__ w1t,
    const float* __restrict__ as0, const float* __restrict__ ad0,
    const float* __restrict__ b0g,
    const float* __restrict__ as1, const float* __restrict__ ad1,
    const float* __restrict__ b1g,
    float* __restrict__ out)
{
    const int b = blockIdx.x;
    const int scene = b >> 3, tt = b & 7;
    const int tid = threadIdx.x;
    const int wv = tid >> 6, l = tid & 63, q = l >> 4, r = l & 15;

    __shared__ __attribute__((aligned(16))) float  hf[64 * 68];    // fp32 features / layer outputs
    __shared__ __attribute__((aligned(16))) ushort hb[64 * 72];    // normed h, bf16, A-operand rows
    __shared__ __attribute__((aligned(16))) ushort wb[64 * 72];    // W^T bf16, B-operand rows
    __shared__ __attribute__((aligned(16))) ushort hptb[64 * 72];  // h'^T bf16 (PV B-operand + s/d dots)
    __shared__ float sarr[4][64], darr[4][64], invden[4][64], redA[4][64];
    __shared__ float maskv[64], meanv[64], rstdv[64], asv[64], adv[64];
    __shared__ float bias0[16], bias1[64];
    __shared__ float cntv;

    // ---------------- initial loads ----------------
    {
        const float* xb = x + (size_t)b * 4096;
        #pragma unroll
        for (int k = 0; k < 4; ++k) {
            int idx = k * 1024 + tid * 4;
            float4 v = *(const float4*)(xb + idx);
            int n = idx >> 6, c = idx & 63;
            *(float4*)&hf[n * 68 + c] = v;
        }
        // wb <- w0t (contiguous 9216B image)
        #pragma unroll
        for (int k = 0; k < 3; ++k) {
            int ch = k * 256 + tid;
            if (ch < 576) ((uint4*)wb)[ch] = ((const uint4*)w0t)[ch];
        }
        if (tid < 64)       { asv[tid] = as0[tid]; adv[tid] = ad0[tid]; }
        else if (tid < 128) { bias1[tid - 64] = b1g[tid - 64]; }
        else if (tid < 144) { bias0[tid - 128] = b0g[tid - 128]; }
        if (tid >= 192) {
            int n = tid - 192;
            maskv[n] = (fhi[scene * 64 + n] <= tt) ? 1.0f : 0.0f;
        }
    }
    __syncthreads();

    // -------- masked instance norm: hf (raw, preserved) -> hb (normed bf16) --------
    auto do_norm = [&]() {
        const int g = tid >> 6, c = tid & 63;
        float sum = 0.f;
        #pragma unroll
        for (int k = 0; k < 16; ++k) sum += hf[(g * 16 + k) * 68 + c] * maskv[g * 16 + k];
        redA[g][c] = sum;
        __syncthreads();
        if (tid < 64) {
            float cnt = 0.f;
            #pragma unroll
            for (int m = 0; m < 64; ++m) cnt += maskv[m];
            if (cnt < 0.5f) cnt = 1.0f;
            if (tid == 0) cntv = cnt;
            meanv[tid] = (redA[0][tid] + redA[1][tid] + redA[2][tid] + redA[3][tid]) / cnt;
        }
        __syncthreads();
        float mean = meanv[c];
        float sq = 0.f;
        #pragma unroll
        for (int k = 0; k < 16; ++k) {
            float dv = (hf[(g * 16 + k) * 68 + c] - mean) * maskv[g * 16 + k];
            sq += dv * dv;
        }
        redA[g][c] = sq;
        __syncthreads();
        if (tid < 64) {
            float var = (redA[0][tid] + redA[1][tid] + redA[2][tid] + redA[3][tid]) / cntv;
            rstdv[tid] = rsqrtf(var + 1e-5f);
        }
        __syncthreads();
        #pragma unroll
        for (int k = 0; k < 8; ++k) {        // write normed bf16 pairs
            int p = k * 256 + tid;
            int n = p >> 5, c2 = (p & 31) * 2;
            float2 hv = *(const float2*)&hf[n * 68 + c2];
            uint32_t pk = f2bf((hv.x - meanv[c2]) * rstdv[c2])
                        | (f2bf((hv.y - meanv[c2 + 1]) * rstdv[c2 + 1]) << 16);
            *(uint32_t*)&hb[n * 72 + c2] = pk;
        }
        __syncthreads();
    };

    // -------- h' = hb @ W via MFMA; D-frags -> hptb (bf16, transposed) --------
    auto do_matmul = [&]() {
        short8 af0 = *(const short8*)&hb[(16 * wv + r) * 72 + 8 * q];
        short8 af1 = *(const short8*)&hb[(16 * wv + r) * 72 + 32 + 8 * q];
        floatx4 acc[4];
        #pragma unroll
        for (int ct = 0; ct < 4; ++ct) { acc[ct][0]=0.f; acc[ct][1]=0.f; acc[ct][2]=0.f; acc[ct][3]=0.f; }
        #pragma unroll
        for (int ct = 0; ct < 4; ++ct) {
            short8 b0 = *(const short8*)&wb[(16 * ct + r) * 72 + 8 * q];
            short8 b1 = *(const short8*)&wb[(16 * ct + r) * 72 + 32 + 8 * q];
            acc[ct] = __builtin_amdgcn_mfma_f32_16x16x32_bf16(af0, b0, acc[ct], 0, 0, 0);
            acc[ct] = __builtin_amdgcn_mfma_f32_16x16x32_bf16(af1, b1, acc[ct], 0, 0, 0);
        }
        // D layout: col=r (out feat within tile), row=4q+reg (node). Write transposed bf16.
        #pragma unroll
        for (int ct = 0; ct < 4; ++ct) {
            uint2 pk;
            pk.x = f2bf(acc[ct][0]) | (f2bf(acc[ct][1]) << 16);
            pk.y = f2bf(acc[ct][2]) | (f2bf(acc[ct][3]) << 16);
            *(uint2*)&hptb[(16 * ct + r) * 72 + 16 * wv + 4 * q] = pk;
        }
        __syncthreads();
    };

    // -------- s/d scores: s[h][n] = sum_o hp[n][o]*a[h][o] (per-head 16-dots) --------
    auto do_sd = [&](int layer) {
        const int g = tid >> 6, n = tid & 63;
        const int ob = (g & 1) * 32;
        const float* av = (g < 2) ? asv : adv;
        float p0 = 0.f, p1 = 0.f;
        #pragma unroll
        for (int j = 0; j < 16; ++j) {
            p0 += bf2f(hptb[(ob + j) * 72 + n])      * av[ob + j];
            p1 += bf2f(hptb[(ob + 16 + j) * 72 + n]) * av[ob + 16 + j];
        }
        if (layer == 0) {
            float* tgt = (g < 2) ? &sarr[0][0] : &darr[0][0];
            int hh = (g & 1) * 2;
            tgt[hh * 64 + n] = p0;
            tgt[(hh + 1) * 64 + n] = p1;
        } else {
            redA[g][n] = p0 + p1;
        }
        __syncthreads();
        if (layer == 1) {
            if (g == 0) sarr[0][n] = redA[0][n] + redA[1][n];
            else if (g == 1) darr[0][n] = redA[2][n] + redA[3][n];
            __syncthreads();
        }
    };

    // -------- softmax P (A-frag regs) + PV MFMA + epilogue -> hf --------
    auto do_attn = [&](int layer) {
        const int hd = layer ? 0 : wv;
        // dmax over present m (per head); rowmax[n] = lrelu(s[n]+dmax) by monotonicity
        float dm = (maskv[l] > 0.f) ? darr[hd][l] : NEGV;
        #pragma unroll
        for (int s = 32; s; s >>= 1) dm = fmaxf(dm, __shfl_xor(dm, s, 64));
        const int ntiles = layer ? 1 : 4;
        short8 pf[4][2];
        float rowsum[4];
        for (int t = 0; t < ntiles; ++t) {
            int nb = layer ? 16 * wv : 16 * t;
            int n = nb + r;
            float sv = sarr[hd][n];
            float mk = maskv[n];
            float sdm = sv + dm;
            float rm = fmaxf(sdm, 0.2f * sdm);
            float rs = 0.f;
            #pragma unroll
            for (int ks = 0; ks < 2; ++ks) {
                #pragma unroll
                for (int j = 0; j < 8; ++j) {
                    int m = 32 * ks + 8 * q + j;
                    float v = sv + darr[hd][m];
                    v = fmaxf(v, 0.2f * v);                 // leaky-relu
                    float e = __expf(v - rm);               // <= 1
                    e = (maskv[m] > 0.f) ? e : 0.f;
                    e = (mk > 0.f) ? e : 1.f;               // fully-masked row -> uniform
                    rs += e;
                    ((ushort*)&pf[t][ks])[j] = (ushort)f2bf(e);
                }
            }
            rs += __shfl_xor(rs, 16, 64);
            rs += __shfl_xor(rs, 32, 64);                   // full row sum (over quads)
            rowsum[t] = rs;
        }
        if (l < 16) {
            for (int t = 0; t < ntiles; ++t) {
                int nb = layer ? 16 * wv : 16 * t;
                invden[hd][nb + r] = 1.0f / rowsum[t];
            }
        }
        floatx4 oacc[4];
        #pragma unroll
        for (int i = 0; i < 4; ++i) { oacc[i][0]=0.f; oacc[i][1]=0.f; oacc[i][2]=0.f; oacc[i][3]=0.f; }
        if (layer == 0) {
            // wave = head: O_h[64 x 16] = P_h @ hp[:, head cols]; B from hptb rows 16*hd+r
            short8 bv0 = *(const short8*)&hptb[(16 * hd + r) * 72 + 8 * q];
            short8 bv1 = *(const short8*)&hptb[(16 * hd + r) * 72 + 32 + 8 * q];
            #pragma unroll
            for (int t = 0; t < 4; ++t) {
                oacc[t] = __builtin_amdgcn_mfma_f32_16x16x32_bf16(pf[t][0], bv0, oacc[t], 0, 0, 0);
                oacc[t] = __builtin_amdgcn_mfma_f32_16x16x32_bf16(pf[t][1], bv1, oacc[t], 0, 0, 0);
            }
            // epilogue: rows n=16t+4q+reg, col c=16*wv+r; ELU; concat into hf
            #pragma unroll
            for (int t = 0; t < 4; ++t) {
                #pragma unroll
                for (int reg = 0; reg < 4; ++reg) {
                    int n = 16 * t + 4 * q + reg;
                    float val = oacc[t][reg] * invden[wv][n] + bias0[r];
                    val = (val > 0.f) ? val : (__expf(val) - 1.0f);
                    hf[n * 68 + 16 * wv + r] = val;
                }
            }
        } else {
            // wave = row-tile: O[16 rows x 64] ; B-frags from hptb rows 16*ct+r
            #pragma unroll
            for (int ct = 0; ct < 4; ++ct) {
                short8 bv0 = *(const short8*)&hptb[(16 * ct + r) * 72 + 8 * q];
                short8 bv1 = *(const short8*)&hptb[(16 * ct + r) * 72 + 32 + 8 * q];
                oacc[ct] = __builtin_amdgcn_mfma_f32_16x16x32_bf16(pf[0][0], bv0, oacc[ct], 0, 0, 0);
                oacc[ct] = __builtin_amdgcn_mfma_f32_16x16x32_bf16(pf[0][1], bv1, oacc[ct], 0, 0, 0);
            }
            #pragma unroll
            for (int ct = 0; ct < 4; ++ct) {
                #pragma unroll
                for (int reg = 0; reg < 4; ++reg) {
                    int n = 16 * wv + 4 * q + reg;
                    hf[n * 68 + 16 * ct + r] = oacc[ct][reg] * invden[0][n] + bias1[16 * ct + r];
                }
            }
        }
        __syncthreads();
    };

    // ================= layer 0 =================
    do_norm();
    do_matmul();
    do_sd(0);
    do_attn(0);

    // ================= layer 1 =================
    {   // reload weights + attention vectors (consumers are beyond do_norm's barriers)
        #pragma unroll
        for (int k = 0; k < 3; ++k) {
            int ch = k * 256 + tid;
            if (ch < 576) ((uint4*)wb)[ch] = ((const uint4*)w1t)[ch];
        }
        if (tid < 64) { asv[tid] = as1[tid]; adv[tid] = ad1[tid]; }
    }
    do_norm();
    do_matmul();
    do_sd(1);
    do_attn(1);

    // ---------------- coalesced store ----------------
    {
        float* ob = out + (size_t)b * 4096;
        #pragma unroll
        for (int k = 0; k < 4; ++k) {
            int idx = k * 1024 + tid * 4;
            int n = idx >> 6, c = idx & 63;
            *(float4*)(ob + idx) = *(const float4*)&hf[n * 68 + c];
        }
    }
}

extern "C" void kernel_launch(void* const* d_in, const int* in_sizes, int n_in,
                              void* d_out, int out_size, void* d_ws, size_t ws_size,
                              hipStream_t stream)
{
    const float* x   = (const float*)d_in[0];
    const int*   fhi = (const int*)d_in[1];
    const float* w0  = (const float*)d_in[2];
    const float* as0 = (const float*)d_in[3];
    const float* ad0 = (const float*)d_in[4];
    const float* b0  = (const float*)d_in[5];
    const float* w1  = (const float*)d_in[6];
    const float* as1 = (const float*)d_in[7];
    const float* ad1 = (const float*)d_in[8];
    const float* b1  = (const float*)d_in[9];
    float* o = (float*)d_out;
    ushort* wt = (ushort*)d_ws;   // 2 x 4608 ushorts

    hipLaunchKernelGGL(prep_weights, dim3(2), dim3(256), 0, stream, w0, w1, wt);
    hipLaunchKernelGGL(gat_fused, dim3(8192), dim3(256), 0, stream,
                       x, fhi, wt, wt + 4608, as0, ad0, b0, as1, ad1, b1, o);
}